// Round 15
// baseline (134.869 us; speedup 1.0000x reference)
//
#include <hip/hip_runtime.h>

#define NB 64
#define KP1 129
#define DD 128
#define NROWS 50000
#define EPSF 1e-6f
#define E128F (128.0f*EPSF*EPSF)
#define OUT_SIDE (NB*NB*KP1)            // 528384 per side
#define L2E_T 28.853900817779268f       // log2(e)/T, T=0.05
#define RSQRT_D 0.08838834764831845f    // 1/sqrt(128)
#define NGEMM (2*129)                   // 2 sides x 129 rowblocks of 64 w-rows
#define NCOPY 1024
#define CSTRIDE ((size_t)NCOPY*256)     // 262144 float4 per burst step
#define NBURST 6                        // 6*CSTRIDE = 1,572,864
#define NTAIL 106                       // (1,600,000 - 1,572,864)/256

__device__ __forceinline__ float4 ldf4(const float* p) { return *(const float4*)p; }

// ONE dispatch, r13 gemm structure (35 KB LDS -> 4 blocks/CU) + r14 burst copy.
// k_finish is folded in via counters:
//   gemm blocks: vals in regs -> post Z -> fence+gemmCnt -> spin(258, gemm-only)
//                -> compute f -> write out scaled ONCE.
//   copy blocks: burst copy -> fence+copyCnt; first 32 spin(1024) -> patch rows.
// Spinners: 258 gemm + 32 copy = 290 << 1024 resident slots; all other blocks
// retire freely => no deadlock under any dispatch order.
__global__ __launch_bounds__(256) void k_all(
    const float* __restrict__ v1, const float* __restrict__ v2,
    const float* __restrict__ mem1, const float* __restrict__ mem2,
    const int* __restrict__ y, const int* __restrict__ idx,
    float* __restrict__ dout, double* __restrict__ sums, int* __restrict__ cnts)
{
    const int bid = blockIdx.x;
    const int tid = threadIdx.x;

    if (bid < NGEMM) {
        // ---------------- gemm role ----------------
        __shared__ float A2[64*64];           // [kk][r], current K-half
        __shared__ float B2[64*64];           // [kk][c]
        __shared__ float dotwul[64], swl[64], wql[64];
        __shared__ float sanl[64], anql[64], g1l0[64], g1l1[64];
        __shared__ int   lidxl[64], yl[64];
        __shared__ float sul[2], usql[2];
        __shared__ double lsumd[4];
        __shared__ double fshd;

        const int s  = bid / 129;             // side: 0 -> (v1, mem2), 1 -> (v2, mem1)
        const int rb = bid % 129;
        const float* v   = s ? v2 : v1;
        const float* mem = s ? mem1 : mem2;
        const int a0 = (rb*64) / 129;
        const int a1 = (rb*64 + 63) / 129;    // a0 or a0+1

        const int r  = tid >> 2;              // 0..63: A-row AND B-col index
        const int ch = tid & 3;               // 4 chunk-threads per row, adjacent lanes

        const int g    = rb*64 + r;
        const int ag   = g / 129;
        const int mrow = idx[g];
        const int crow = y[r];
        if (ch == 0) { lidxl[r] = mrow; yl[r] = crow; }

        const float* wrow = mem + (size_t)mrow*DD;
        const float* urow = v   + (size_t)ag*DD;
        const float* brow = mem + (size_t)crow*DD;
        const float* u0p  = v   + (size_t)a0*DD;
        const float* u1p  = v   + (size_t)a1*DD;

        // ---- u stats: Su, ||u||^2 for a0, a1 (8 threads, shuffle-reduced) ----
        if (tid < 8) {
            const int au = tid & 1, c2 = tid >> 1;
            const float* up = au ? u1p : u0p;
            float ps = 0.f, pq = 0.f;
            #pragma unroll
            for (int i = 0; i < 8; ++i) {
                float4 uu = ldf4(up + c2*32 + i*4);
                ps += (uu.x + uu.y) + (uu.z + uu.w);
                pq = fmaf(uu.x,uu.x, fmaf(uu.y,uu.y, fmaf(uu.z,uu.z, fmaf(uu.w,uu.w, pq))));
            }
            ps += __shfl_xor(ps, 2, 64); pq += __shfl_xor(pq, 2, 64);
            ps += __shfl_xor(ps, 4, 64); pq += __shfl_xor(pq, 4, 64);
            if (tid < 2) { sul[au] = ps; usql[au] = pq; }
        }

        // ---- 2 K-halves of 64: stage + stats, GEMM each half ----
        const int r0 = (tid >> 4) << 2;
        const int c0 = (tid & 15) << 2;
        float acc[4][4] = {{0.f,0.f,0.f,0.f},{0.f,0.f,0.f,0.f},{0.f,0.f,0.f,0.f},{0.f,0.f,0.f,0.f}};
        float pd=0.f, ps=0.f, pq=0.f;         // A-row stats: w·u, Sw, Sww
        float pn=0.f, pqB=0.f, p0=0.f, p1=0.f;// B-col stats: San, Sanan, an·u0, an·u1

        #pragma unroll
        for (int h = 0; h < 2; ++h) {
            const int base = h*64 + ch*16;
            #pragma unroll
            for (int i = 0; i < 4; ++i) {
                const int kl = ch*16 + i*4;
                float4 w  = ldf4(wrow + base + i*4);
                float4 uu = ldf4(urow + base + i*4);
                A2[(kl+0)*64 + r] = w.x;
                A2[(kl+1)*64 + r] = w.y;
                A2[(kl+2)*64 + r] = w.z;
                A2[(kl+3)*64 + r] = w.w;
                pd = fmaf(w.x,uu.x, fmaf(w.y,uu.y, fmaf(w.z,uu.z, fmaf(w.w,uu.w, pd))));
                ps += (w.x + w.y) + (w.z + w.w);
                pq = fmaf(w.x,w.x, fmaf(w.y,w.y, fmaf(w.z,w.z, fmaf(w.w,w.w, pq))));
                float4 an = ldf4(brow + base + i*4);
                float4 q0 = ldf4(u0p  + base + i*4);
                float4 q1 = ldf4(u1p  + base + i*4);
                B2[(kl+0)*64 + r] = an.x;
                B2[(kl+1)*64 + r] = an.y;
                B2[(kl+2)*64 + r] = an.z;
                B2[(kl+3)*64 + r] = an.w;
                pn += (an.x + an.y) + (an.z + an.w);
                pqB = fmaf(an.x,an.x, fmaf(an.y,an.y, fmaf(an.z,an.z, fmaf(an.w,an.w, pqB))));
                p0 = fmaf(an.x,q0.x, fmaf(an.y,q0.y, fmaf(an.z,q0.z, fmaf(an.w,q0.w, p0))));
                p1 = fmaf(an.x,q1.x, fmaf(an.y,q1.y, fmaf(an.z,q1.z, fmaf(an.w,q1.w, p1))));
            }
            __syncthreads();
            #pragma unroll 8
            for (int kk = 0; kk < 64; ++kk) {
                float4 av = *(float4*)&A2[kk*64 + r0];
                float4 bv = *(float4*)&B2[kk*64 + c0];
                acc[0][0]=fmaf(av.x,bv.x,acc[0][0]); acc[0][1]=fmaf(av.x,bv.y,acc[0][1]);
                acc[0][2]=fmaf(av.x,bv.z,acc[0][2]); acc[0][3]=fmaf(av.x,bv.w,acc[0][3]);
                acc[1][0]=fmaf(av.y,bv.x,acc[1][0]); acc[1][1]=fmaf(av.y,bv.y,acc[1][1]);
                acc[1][2]=fmaf(av.y,bv.z,acc[1][2]); acc[1][3]=fmaf(av.y,bv.w,acc[1][3]);
                acc[2][0]=fmaf(av.z,bv.x,acc[2][0]); acc[2][1]=fmaf(av.z,bv.y,acc[2][1]);
                acc[2][2]=fmaf(av.z,bv.z,acc[2][2]); acc[2][3]=fmaf(av.z,bv.w,acc[2][3]);
                acc[3][0]=fmaf(av.w,bv.x,acc[3][0]); acc[3][1]=fmaf(av.w,bv.y,acc[3][1]);
                acc[3][2]=fmaf(av.w,bv.z,acc[3][2]); acc[3][3]=fmaf(av.w,bv.w,acc[3][3]);
            }
            __syncthreads();                  // half done; safe to restage
        }

        // ---- reduce stats across the 4 chunk-lanes (adjacent), publish ----
        pd += __shfl_xor(pd, 1, 64); ps += __shfl_xor(ps, 1, 64); pq += __shfl_xor(pq, 1, 64);
        pn += __shfl_xor(pn, 1, 64); pqB += __shfl_xor(pqB, 1, 64);
        p0 += __shfl_xor(p0, 1, 64); p1 += __shfl_xor(p1, 1, 64);
        pd += __shfl_xor(pd, 2, 64); ps += __shfl_xor(ps, 2, 64); pq += __shfl_xor(pq, 2, 64);
        pn += __shfl_xor(pn, 2, 64); pqB += __shfl_xor(pqB, 2, 64);
        p0 += __shfl_xor(p0, 2, 64); p1 += __shfl_xor(p1, 2, 64);
        if (ch == 0) {
            dotwul[r] = pd; swl[r] = ps; wql[r] = pq;
            sanl[r] = pn; anql[r] = pqB; g1l0[r] = p0; g1l1[r] = p1;
        }
        __syncthreads();

        // ---- epilogue: values into registers, Z partial ----
        float fval[16];
        float dwr[4], swr[4], wqr[4];
        int   idr[4], aur[4];
        size_t obase[4];
        #pragma unroll
        for (int i = 0; i < 4; ++i) {
            const int rr = r0 + i, gg = rb*64 + rr;
            const int aa = gg / 129, kk = gg - aa*129;
            dwr[i] = dotwul[rr]; swr[i] = swl[rr]; wqr[i] = wql[rr];
            idr[i] = lidxl[rr];  aur[i] = aa - a0;
            obase[i] = (size_t)s*OUT_SIDE + (size_t)(aa*64)*129 + kk;
        }
        double zacc = 0.0;
        #pragma unroll
        for (int j = 0; j < 4; ++j) {
            const int b = c0 + j;
            const float sanb = sanl[b], anqb = anql[b];
            const int yb = yl[b];
            const float g1v[2] = { g1l0[b], g1l1[b] };
            float rdu[2], vem[2];
            #pragma unroll
            for (int au = 0; au < 2; ++au) {
                const float du2 = usql[au] - 2.f*g1v[au] + anqb
                                + 2.f*EPSF*(sul[au] - sanb) + E128F;
                rdu[au] = rsqrtf(fmaxf(du2, 1e-20f));
                vem[au] = exp2f((sul[au] - sanb + 128.f*EPSF) * rdu[au] * (RSQRT_D*L2E_T));
            }
            #pragma unroll
            for (int i = 0; i < 4; ++i) {
                const int au = aur[i];
                const float C2 = acc[i][j];
                const float N = dwr[i] - C2 - g1v[au] + anqb
                              + EPSF*(swr[i] + sul[au] - 2.f*sanb) + E128F;
                const float dw2 = wqr[i] - 2.f*C2 + anqb
                                + 2.f*EPSF*(swr[i] - sanb) + E128F;
                float val = exp2f(N * rsqrtf(fmaxf(dw2, 1e-20f)) * rdu[au] * L2E_T);
                if (idr[i] == yb) val = vem[au];
                fval[j*4 + i] = val;
                zacc += (double)val;
            }
        }
        // in-wave f64 reduce; block total -> this block's slot
        #pragma unroll
        for (int m = 1; m < 64; m <<= 1) zacc += __shfl_xor(zacc, m, 64);
        if ((tid & 63) == 0) lsumd[tid >> 6] = zacc;
        __syncthreads();
        if (tid == 0) {
            sums[s*129 + rb] = (lsumd[0] + lsumd[1]) + (lsumd[2] + lsumd[3]);
            __threadfence();
            atomicAdd(&cnts[0], 1);
            // spin: only gemm blocks wait, only on gemm blocks (1/CU, bounded)
            while (__hip_atomic_load(&cnts[0], __ATOMIC_ACQUIRE,
                                     __HIP_MEMORY_SCOPE_AGENT) < NGEMM)
                __builtin_amdgcn_s_sleep(4);
        }
        __syncthreads();
        // ---- this side's Z -> scale f, broadcast ----
        if (tid < 64) {
            double z  = __hip_atomic_load(&sums[s*129 + tid],      __ATOMIC_ACQUIRE, __HIP_MEMORY_SCOPE_AGENT)
                      + __hip_atomic_load(&sums[s*129 + 64 + tid], __ATOMIC_ACQUIRE, __HIP_MEMORY_SCOPE_AGENT);
            if (tid == 0)
                z += __hip_atomic_load(&sums[s*129 + 128], __ATOMIC_ACQUIRE, __HIP_MEMORY_SCOPE_AGENT);
            #pragma unroll
            for (int m = 1; m < 64; m <<= 1) z += __shfl_xor(z, m, 64);
            if (tid == 0) fshd = (double)OUT_SIDE / (z * (double)NROWS);
        }
        __syncthreads();
        const float f = (float)fshd;
        #pragma unroll
        for (int j = 0; j < 4; ++j)
            #pragma unroll
            for (int i = 0; i < 4; ++i)
                dout[obase[i] + (size_t)(c0 + j)*129] = fval[j*4 + i] * f;
    } else {
        // ---------------- copy role: single deep burst ----------------
        float* nm1 = dout + (size_t)2*OUT_SIDE;
        float* nm2 = nm1 + (size_t)NROWS*DD;
        const int cid = bid - NGEMM;                  // 0..NCOPY-1
        const float4* s1 = (const float4*)mem1;
        const float4* s2 = (const float4*)mem2;
        float4* d1 = (float4*)nm1;
        float4* d2 = (float4*)nm2;
        const size_t i0 = (size_t)cid*256 + tid;

        float4 a[NBURST], b[NBURST];
        #pragma unroll
        for (int j = 0; j < NBURST; ++j) {
            a[j] = s1[i0 + (size_t)j*CSTRIDE];
            b[j] = s2[i0 + (size_t)j*CSTRIDE];
        }
        #pragma unroll
        for (int j = 0; j < NBURST; ++j) {
            d1[i0 + (size_t)j*CSTRIDE] = a[j];
            d2[i0 + (size_t)j*CSTRIDE] = b[j];
        }
        if (cid < NTAIL) {
            const size_t it = i0 + (size_t)NBURST*CSTRIDE;
            d1[it] = s1[it];
            d2[it] = s2[it];
        }
        __syncthreads();
        if (tid == 0) {
            __threadfence();
            atomicAdd(&cnts[1], 1);
        }
        if (cid < 32) {
            // patch role: wait for whole copy, then overwrite updated rows
            if (tid == 0) {
                while (__hip_atomic_load(&cnts[1], __ATOMIC_ACQUIRE,
                                         __HIP_MEMORY_SCOPE_AGENT) < NCOPY)
                    __builtin_amdgcn_s_sleep(4);
            }
            __syncthreads();
            const int bank = cid >> 4;
            const int wave = tid >> 6;
            const int lane = tid & 63;
            const int b    = (cid & 15) * 4 + wave;
            const float* mem = bank ? mem2 : mem1;
            const float* v   = bank ? v2 : v1;
            float* nm = bank ? nm2 : nm1;

            const int row = y[b];
            bool skip = false;
            for (int b2 = b + 1; b2 < NB; ++b2) skip |= (y[b2] == row);  // last wins
            if (!skip) {
                const float2 m2 = *(const float2*)(mem + (size_t)row*DD + lane*2);
                const float2 w2 = *(const float2*)(v + (size_t)b*DD + lane*2);
                float px = 0.5f*(m2.x + w2.x);
                float py = 0.5f*(m2.y + w2.y);
                float ss = px*px + py*py;
                #pragma unroll
                for (int m = 1; m < 64; m <<= 1) ss += __shfl_xor(ss, m, 64);
                const float rn = 1.0f / sqrtf(ss);
                *(float2*)(nm + (size_t)row*DD + lane*2) = make_float2(px*rn, py*rn);
            }
        }
    }
}

extern "C" void kernel_launch(void* const* d_in, const int* in_sizes, int n_in,
                              void* d_out, int out_size, void* d_ws, size_t ws_size,
                              hipStream_t stream) {
    const float* v1   = (const float*)d_in[0];
    const float* v2   = (const float*)d_in[1];
    const float* mem1 = (const float*)d_in[2];
    const float* mem2 = (const float*)d_in[3];
    const int*   y    = (const int*)d_in[4];
    const int*   idx  = (const int*)d_in[5];
    float*  out  = (float*)d_out;
    int*    cnts = (int*)d_ws;                        // [0]=gemm done, [1]=copy done
    double* sums = (double*)((char*)d_ws + 64);       // 258 slots

    hipMemsetAsync(d_ws, 0, 64, stream);
    k_all<<<NGEMM + NCOPY, 256, 0, stream>>>(v1, v2, mem1, mem2, y, idx, out, sums, cnts);
}

// Round 16
// 31.877 us; speedup vs baseline: 4.2309x; 4.2309x over previous
//
#include <hip/hip_runtime.h>

#define NB 64
#define KP1 129
#define DD 128
#define NROWS 50000
#define EPSF 1e-6f
#define E128F (128.0f*EPSF*EPSF)
#define OUT_SIDE (NB*NB*KP1)            // 528384 per side
#define L2E_T 28.853900817779268f       // log2(e)/T, T=0.05
#define RSQRT_D 0.08838834764831845f    // 1/sqrt(128)
#define NGEMM (2*129)                   // 2 sides x 129 rowblocks of 64 w-rows
#define NCOPY 1024
#define CSTRIDE ((size_t)NCOPY*256)     // 262144 float4 per burst step
#define NBURST 6                        // 6*CSTRIDE = 1,572,864
#define NTAIL 106                       // (1,600,000 - 1,572,864)/256

typedef float f32x4 __attribute__((ext_vector_type(4)));

__device__ __forceinline__ float4 ldf4(const float* p) { return *(const float4*)p; }

// r14 champion (32.0 us) with ONE isolated change: the bank-copy DESTINATION
// stores are non-temporal (bypass L2/L3). Mechanism: cached copy-writes
// re-dirty 51 MB of L3 every replay, evicting the L3-resident source banks
// (measured FETCH ~30 MB that should be ~0). NT writes stream to HBM and
// leave L3 to hold the banks + out. Everything else byte-identical to r14.
__global__ __launch_bounds__(256) void k_big(
    const float* __restrict__ v1, const float* __restrict__ v2,
    const float* __restrict__ mem1, const float* __restrict__ mem2,
    const int* __restrict__ y, const int* __restrict__ idx,
    float* __restrict__ dout, double* __restrict__ sums)
{
    const int bid = blockIdx.x;
    const int tid = threadIdx.x;

    if (bid < NGEMM) {
        // ---------------- gemm role (identical to r13/r14) ----------------
        __shared__ float A2[64*64];           // [kk][r], current K-half
        __shared__ float B2[64*64];           // [kk][c]
        __shared__ float dotwul[64], swl[64], wql[64];
        __shared__ float sanl[64], anql[64], g1l0[64], g1l1[64];
        __shared__ int   lidxl[64], yl[64];
        __shared__ float sul[2], usql[2];
        __shared__ double lsumd[4];

        const int s  = bid / 129;             // side: 0 -> (v1, mem2), 1 -> (v2, mem1)
        const int rb = bid % 129;
        const float* v   = s ? v2 : v1;
        const float* mem = s ? mem1 : mem2;
        const int a0 = (rb*64) / 129;
        const int a1 = (rb*64 + 63) / 129;    // a0 or a0+1

        const int r  = tid >> 2;              // 0..63: A-row AND B-col index
        const int ch = tid & 3;               // 4 chunk-threads per row, adjacent lanes

        const int g    = rb*64 + r;
        const int ag   = g / 129;
        const int mrow = idx[g];
        const int crow = y[r];
        if (ch == 0) { lidxl[r] = mrow; yl[r] = crow; }

        const float* wrow = mem + (size_t)mrow*DD;
        const float* urow = v   + (size_t)ag*DD;
        const float* brow = mem + (size_t)crow*DD;
        const float* u0p  = v   + (size_t)a0*DD;
        const float* u1p  = v   + (size_t)a1*DD;

        // ---- u stats: Su, ||u||^2 for a0, a1 (8 threads, shuffle-reduced) ----
        if (tid < 8) {
            const int au = tid & 1, c2 = tid >> 1;
            const float* up = au ? u1p : u0p;
            float ps = 0.f, pq = 0.f;
            #pragma unroll
            for (int i = 0; i < 8; ++i) {
                float4 uu = ldf4(up + c2*32 + i*4);
                ps += (uu.x + uu.y) + (uu.z + uu.w);
                pq = fmaf(uu.x,uu.x, fmaf(uu.y,uu.y, fmaf(uu.z,uu.z, fmaf(uu.w,uu.w, pq))));
            }
            ps += __shfl_xor(ps, 2, 64); pq += __shfl_xor(pq, 2, 64);
            ps += __shfl_xor(ps, 4, 64); pq += __shfl_xor(pq, 4, 64);
            if (tid < 2) { sul[au] = ps; usql[au] = pq; }
        }

        // ---- 2 K-halves of 64: stage + stats, GEMM each half ----
        const int r0 = (tid >> 4) << 2;
        const int c0 = (tid & 15) << 2;
        float acc[4][4] = {{0.f,0.f,0.f,0.f},{0.f,0.f,0.f,0.f},{0.f,0.f,0.f,0.f},{0.f,0.f,0.f,0.f}};
        float pd=0.f, ps=0.f, pq=0.f;         // A-row stats: w·u, Sw, Sww
        float pn=0.f, pqB=0.f, p0=0.f, p1=0.f;// B-col stats: San, Sanan, an·u0, an·u1

        #pragma unroll
        for (int h = 0; h < 2; ++h) {
            const int base = h*64 + ch*16;
            #pragma unroll
            for (int i = 0; i < 4; ++i) {
                const int kl = ch*16 + i*4;
                float4 w  = ldf4(wrow + base + i*4);
                float4 uu = ldf4(urow + base + i*4);
                A2[(kl+0)*64 + r] = w.x;
                A2[(kl+1)*64 + r] = w.y;
                A2[(kl+2)*64 + r] = w.z;
                A2[(kl+3)*64 + r] = w.w;
                pd = fmaf(w.x,uu.x, fmaf(w.y,uu.y, fmaf(w.z,uu.z, fmaf(w.w,uu.w, pd))));
                ps += (w.x + w.y) + (w.z + w.w);
                pq = fmaf(w.x,w.x, fmaf(w.y,w.y, fmaf(w.z,w.z, fmaf(w.w,w.w, pq))));
                float4 an = ldf4(brow + base + i*4);
                float4 q0 = ldf4(u0p  + base + i*4);
                float4 q1 = ldf4(u1p  + base + i*4);
                B2[(kl+0)*64 + r] = an.x;
                B2[(kl+1)*64 + r] = an.y;
                B2[(kl+2)*64 + r] = an.z;
                B2[(kl+3)*64 + r] = an.w;
                pn += (an.x + an.y) + (an.z + an.w);
                pqB = fmaf(an.x,an.x, fmaf(an.y,an.y, fmaf(an.z,an.z, fmaf(an.w,an.w, pqB))));
                p0 = fmaf(an.x,q0.x, fmaf(an.y,q0.y, fmaf(an.z,q0.z, fmaf(an.w,q0.w, p0))));
                p1 = fmaf(an.x,q1.x, fmaf(an.y,q1.y, fmaf(an.z,q1.z, fmaf(an.w,q1.w, p1))));
            }
            __syncthreads();
            #pragma unroll 8
            for (int kk = 0; kk < 64; ++kk) {
                float4 av = *(float4*)&A2[kk*64 + r0];
                float4 bv = *(float4*)&B2[kk*64 + c0];
                acc[0][0]=fmaf(av.x,bv.x,acc[0][0]); acc[0][1]=fmaf(av.x,bv.y,acc[0][1]);
                acc[0][2]=fmaf(av.x,bv.z,acc[0][2]); acc[0][3]=fmaf(av.x,bv.w,acc[0][3]);
                acc[1][0]=fmaf(av.y,bv.x,acc[1][0]); acc[1][1]=fmaf(av.y,bv.y,acc[1][1]);
                acc[1][2]=fmaf(av.y,bv.z,acc[1][2]); acc[1][3]=fmaf(av.y,bv.w,acc[1][3]);
                acc[2][0]=fmaf(av.z,bv.x,acc[2][0]); acc[2][1]=fmaf(av.z,bv.y,acc[2][1]);
                acc[2][2]=fmaf(av.z,bv.z,acc[2][2]); acc[2][3]=fmaf(av.z,bv.w,acc[2][3]);
                acc[3][0]=fmaf(av.w,bv.x,acc[3][0]); acc[3][1]=fmaf(av.w,bv.y,acc[3][1]);
                acc[3][2]=fmaf(av.w,bv.z,acc[3][2]); acc[3][3]=fmaf(av.w,bv.w,acc[3][3]);
            }
            __syncthreads();                  // half done; safe to restage
        }

        // ---- reduce stats across the 4 chunk-lanes (adjacent), publish ----
        pd += __shfl_xor(pd, 1, 64); ps += __shfl_xor(ps, 1, 64); pq += __shfl_xor(pq, 1, 64);
        pn += __shfl_xor(pn, 1, 64); pqB += __shfl_xor(pqB, 1, 64);
        p0 += __shfl_xor(p0, 1, 64); p1 += __shfl_xor(p1, 1, 64);
        pd += __shfl_xor(pd, 2, 64); ps += __shfl_xor(ps, 2, 64); pq += __shfl_xor(pq, 2, 64);
        pn += __shfl_xor(pn, 2, 64); pqB += __shfl_xor(pqB, 2, 64);
        p0 += __shfl_xor(p0, 2, 64); p1 += __shfl_xor(p1, 2, 64);
        if (ch == 0) {
            dotwul[r] = pd; swl[r] = ps; wql[r] = pq;
            sanl[r] = pn; anql[r] = pqB; g1l0[r] = p0; g1l1[r] = p1;
        }
        __syncthreads();

        // ---- epilogue: assemble, exp, write out (unscaled), Z partial ----
        float dwr[4], swr[4], wqr[4];
        int   idr[4], aur[4];
        size_t obase[4];
        #pragma unroll
        for (int i = 0; i < 4; ++i) {
            const int rr = r0 + i, gg = rb*64 + rr;
            const int aa = gg / 129, kk = gg - aa*129;
            dwr[i] = dotwul[rr]; swr[i] = swl[rr]; wqr[i] = wql[rr];
            idr[i] = lidxl[rr];  aur[i] = aa - a0;
            obase[i] = (size_t)s*OUT_SIDE + (size_t)(aa*64)*129 + kk;
        }
        double zacc = 0.0;
        #pragma unroll
        for (int j = 0; j < 4; ++j) {
            const int b = c0 + j;
            const float sanb = sanl[b], anqb = anql[b];
            const int yb = yl[b];
            const float g1v[2] = { g1l0[b], g1l1[b] };
            float rdu[2], vem[2];
            #pragma unroll
            for (int au = 0; au < 2; ++au) {
                const float du2 = usql[au] - 2.f*g1v[au] + anqb
                                + 2.f*EPSF*(sul[au] - sanb) + E128F;
                rdu[au] = rsqrtf(fmaxf(du2, 1e-20f));
                vem[au] = exp2f((sul[au] - sanb + 128.f*EPSF) * rdu[au] * (RSQRT_D*L2E_T));
            }
            #pragma unroll
            for (int i = 0; i < 4; ++i) {
                const int au = aur[i];
                const float C2 = acc[i][j];
                const float N = dwr[i] - C2 - g1v[au] + anqb
                              + EPSF*(swr[i] + sul[au] - 2.f*sanb) + E128F;
                const float dw2 = wqr[i] - 2.f*C2 + anqb
                                + 2.f*EPSF*(swr[i] - sanb) + E128F;
                float val = exp2f(N * rsqrtf(fmaxf(dw2, 1e-20f)) * rdu[au] * L2E_T);
                if (idr[i] == yb) val = vem[au];
                dout[obase[i] + (size_t)b*129] = val;
                zacc += (double)val;
            }
        }
        // in-wave f64 reduce; lane 0 per wave -> lsumd; block total -> slot
        #pragma unroll
        for (int m = 1; m < 64; m <<= 1) zacc += __shfl_xor(zacc, m, 64);
        if ((tid & 63) == 0) lsumd[tid >> 6] = zacc;
        __syncthreads();
        if (tid == 0)
            sums[s*129 + rb] = (lsumd[0] + lsumd[1]) + (lsumd[2] + lsumd[3]);
    } else {
        // ---------------- bank copy role: deep burst, NT dst stores ----------------
        float* nm1 = dout + (size_t)2*OUT_SIDE;
        float* nm2 = nm1 + (size_t)NROWS*DD;
        const int cid = bid - NGEMM;                  // 0..NCOPY-1
        const float* s1 = mem1;
        const float* s2 = mem2;
        const size_t i0 = (size_t)cid*256 + tid;

        f32x4 a[NBURST], b[NBURST];
        #pragma unroll
        for (int j = 0; j < NBURST; ++j) {            // 12 loads, all in flight (cached)
            a[j] = *(const f32x4*)(s1 + 4*(i0 + (size_t)j*CSTRIDE));
            b[j] = *(const f32x4*)(s2 + 4*(i0 + (size_t)j*CSTRIDE));
        }
        #pragma unroll
        for (int j = 0; j < NBURST; ++j) {            // 12 NT stores (bypass L2/L3)
            __builtin_nontemporal_store(a[j], (f32x4*)(nm1 + 4*(i0 + (size_t)j*CSTRIDE)));
            __builtin_nontemporal_store(b[j], (f32x4*)(nm2 + 4*(i0 + (size_t)j*CSTRIDE)));
        }
        if (cid < NTAIL) {                            // ragged tail
            const size_t it = i0 + (size_t)NBURST*CSTRIDE;
            f32x4 ta = *(const f32x4*)(s1 + 4*it);
            f32x4 tb = *(const f32x4*)(s2 + 4*it);
            __builtin_nontemporal_store(ta, (f32x4*)(nm1 + 4*it));
            __builtin_nontemporal_store(tb, (f32x4*)(nm2 + 4*it));
        }
    }
}

// Finish: scale out by 1/Z per side; patch the 128 momentum-updated rows.
__global__ __launch_bounds__(256) void k_finish(
    const float* __restrict__ v1, const float* __restrict__ v2,
    const float* __restrict__ mem1, const float* __restrict__ mem2,
    const int* __restrict__ y,
    float* __restrict__ dout, const double* __restrict__ sums)
{
    const int bid = blockIdx.x;
    const int tid = threadIdx.x;

    if (bid < 32) {
        const int bank = bid >> 4;
        const int wave = tid >> 6;
        const int lane = tid & 63;
        const int b    = (bid & 15) * 4 + wave;
        const float* mem = bank ? mem2 : mem1;
        const float* v   = bank ? v2 : v1;
        float* nm = dout + (size_t)2*OUT_SIDE + (size_t)bank*NROWS*DD;

        const int row = y[b];
        bool skip = false;
        for (int b2 = b + 1; b2 < NB; ++b2) skip |= (y[b2] == row);  // last occurrence wins
        if (!skip) {
            const float2 m2 = *(const float2*)(mem + (size_t)row*DD + lane*2);
            const float2 w2 = *(const float2*)(v + (size_t)b*DD + lane*2);
            float px = 0.5f*(m2.x + w2.x);
            float py = 0.5f*(m2.y + w2.y);
            float ss = px*px + py*py;
            #pragma unroll
            for (int m = 1; m < 64; m <<= 1) ss += __shfl_xor(ss, m, 64);
            const float rn = 1.0f / sqrtf(ss);
            *(float2*)(nm + (size_t)row*DD + lane*2) = make_float2(px*rn, py*rn);
        }
    } else {
        __shared__ double fsh;
        const size_t i = (size_t)(bid - 32)*256 + tid;   // float4 index into out region
        const int side = (i >= (size_t)OUT_SIDE/4) ? 1 : 0;
        // wave 0 reduces this side's 129 per-block Z partials, broadcasts via LDS
        if (tid < 64) {
            double z = sums[side*129 + tid] + sums[side*129 + 64 + tid];
            if (tid == 0) z += sums[side*129 + 128];
            #pragma unroll
            for (int m = 1; m < 64; m <<= 1) z += __shfl_xor(z, m, 64);
            if (tid == 0) fsh = (double)OUT_SIDE / (z * (double)NROWS);
        }
        __syncthreads();
        const float f = (float)fsh;
        float4* io = (float4*)dout;
        float4 t = io[i];
        t.x *= f; t.y *= f; t.z *= f; t.w *= f;
        io[i] = t;
    }
}

extern "C" void kernel_launch(void* const* d_in, const int* in_sizes, int n_in,
                              void* d_out, int out_size, void* d_ws, size_t ws_size,
                              hipStream_t stream) {
    const float* v1   = (const float*)d_in[0];
    const float* v2   = (const float*)d_in[1];
    const float* mem1 = (const float*)d_in[2];
    const float* mem2 = (const float*)d_in[3];
    const int*   y    = (const int*)d_in[4];
    const int*   idx  = (const int*)d_in[5];
    float*  out  = (float*)d_out;
    double* sums = (double*)d_ws;

    k_big<<<NGEMM + NCOPY, 256, 0, stream>>>(v1, v2, mem1, mem2, y, idx, out, sums);
    k_finish<<<32 + (2*OUT_SIDE/4)/256, 256, 0, stream>>>(v1, v2, mem1, mem2, y, out, sums);
}